// Round 4
// baseline (723.364 us; speedup 1.0000x reference)
//
#include <hip/hip_runtime.h>

typedef _Float16 f16;
typedef _Float16 f16x8 __attribute__((ext_vector_type(8)));
typedef _Float16 f16x4 __attribute__((ext_vector_type(4)));
typedef float f32x16 __attribute__((ext_vector_type(16)));

#define BS 65536
#define D 768
#define H 12
#define RB 128                   // rows per main block
#define NBLK ((BS / RB) * H)     // 6144
#define W_ELEMS ((size_t)D * D)
#define XN_ELEMS ((size_t)BS * D)

typedef const __attribute__((address_space(1))) void gvoid_t;
typedef __attribute__((address_space(3))) void lvoid_t;

// ---------------- prepass 1: LayerNorm -> xn (f16, gamma/beta folded), single pass ----------------
// Wave handles 2 rows: lane owns f32 [lane*12, lane*12+12) of each row (x read exactly once).
// Output repacked through a tiny per-wave LDS row buffer so stores are dense 16B dwordx4.
__global__ __launch_bounds__(256, 4) void ln_kernel(const float* __restrict__ x,
                                                    const float* __restrict__ gamma,
                                                    const float* __restrict__ beta,
                                                    f16* __restrict__ xn) {
  __shared__ f16 sRow[4][2 * D];   // 12 KB
  int wave = threadIdx.x >> 6, lane = threadIdx.x & 63;
  size_t row0 = ((size_t)blockIdx.x * 4 + wave) * 2;
  const float4* xr0 = (const float4*)(x + row0 * D) + lane * 3;
  const float4* xr1 = (const float4*)(x + (row0 + 1) * D) + lane * 3;
  float4 u0 = xr0[0], u1 = xr0[1], u2 = xr0[2];
  float4 w0 = xr1[0], w1 = xr1[1], w2 = xr1[2];

  float s0 = (u0.x + u0.y) + (u0.z + u0.w) + (u1.x + u1.y) + (u1.z + u1.w)
           + (u2.x + u2.y) + (u2.z + u2.w);
  float q0 = u0.x*u0.x + u0.y*u0.y + u0.z*u0.z + u0.w*u0.w
           + u1.x*u1.x + u1.y*u1.y + u1.z*u1.z + u1.w*u1.w
           + u2.x*u2.x + u2.y*u2.y + u2.z*u2.z + u2.w*u2.w;
  float s1 = (w0.x + w0.y) + (w0.z + w0.w) + (w1.x + w1.y) + (w1.z + w1.w)
           + (w2.x + w2.y) + (w2.z + w2.w);
  float q1 = w0.x*w0.x + w0.y*w0.y + w0.z*w0.z + w0.w*w0.w
           + w1.x*w1.x + w1.y*w1.y + w1.z*w1.z + w1.w*w1.w
           + w2.x*w2.x + w2.y*w2.y + w2.z*w2.z + w2.w*w2.w;
#pragma unroll
  for (int d2 = 1; d2 <= 32; d2 <<= 1) {
    s0 += __shfl_xor(s0, d2, 64); q0 += __shfl_xor(q0, d2, 64);
    s1 += __shfl_xor(s1, d2, 64); q1 += __shfl_xor(q1, d2, 64);
  }
  float mu0 = s0 * (1.0f / D), rs0 = rsqrtf(q0 * (1.0f / D) - mu0 * mu0 + 1e-6f);
  float mu1 = s1 * (1.0f / D), rs1 = rsqrtf(q1 * (1.0f / D) - mu1 * mu1 + 1e-6f);

  const float4* g4 = (const float4*)(gamma) + lane * 3;
  const float4* b4 = (const float4*)(beta)  + lane * 3;
  float4 g0 = g4[0], g1 = g4[1], g2 = g4[2];
  float4 b0 = b4[0], b1 = b4[1], b2 = b4[2];

  f16* sw = &sRow[wave][lane * 12];
#define NRM4(dst, off, V, G, B, MU, RS)                        \
  { f16x4 o;                                                   \
    o[0] = (f16)((V.x - MU) * RS * G.x + B.x);                 \
    o[1] = (f16)((V.y - MU) * RS * G.y + B.y);                 \
    o[2] = (f16)((V.z - MU) * RS * G.z + B.z);                 \
    o[3] = (f16)((V.w - MU) * RS * G.w + B.w);                 \
    *(f16x4*)(dst + off) = o; }
  NRM4(sw, 0, u0, g0, b0, mu0, rs0)
  NRM4(sw, 4, u1, g1, b1, mu0, rs0)
  NRM4(sw, 8, u2, g2, b2, mu0, rs0)
  NRM4(sw, D + 0, w0, g0, b0, mu1, rs1)
  NRM4(sw, D + 4, w1, g1, b1, mu1, rs1)
  NRM4(sw, D + 8, w2, g2, b2, mu1, rs1)
#undef NRM4
  // same-wave LDS write->read: drain and fence the scheduler
  __builtin_amdgcn_sched_barrier(0);
  asm volatile("s_waitcnt lgkmcnt(0)" ::: "memory");
  __builtin_amdgcn_sched_barrier(0);
  f16* xo = xn + row0 * D;
#pragma unroll
  for (int j = 0; j < 3; ++j) {
    int c = j * 64 + lane;  // 192 chunks of 8 f16 covering both rows
    f16x8 v = *(const f16x8*)(&sRow[wave][c * 8]);
    *(f16x8*)(xo + c * 8) = v;
  }
}

// ---------------- prepass 2: W f32 -> f16 ----------------
__global__ __launch_bounds__(256, 4) void wconv_kernel(const float* __restrict__ Wq,
                                                       const float* __restrict__ Wk,
                                                       const float* __restrict__ Wv,
                                                       f16* __restrict__ wf) {
  int b = blockIdx.x;          // 0..863 (3 * 288)
  int m = b / 288;
  size_t e = ((size_t)(b % 288) * 256 + threadIdx.x) * 8;
  const float* src = (m == 0 ? Wq : (m == 1 ? Wk : Wv)) + e;
  float4 v0 = *(const float4*)src;
  float4 v1 = *(const float4*)(src + 4);
  f16x8 o;
  o[0] = (f16)v0.x; o[1] = (f16)v0.y; o[2] = (f16)v0.z; o[3] = (f16)v0.w;
  o[4] = (f16)v1.x; o[5] = (f16)v1.y; o[6] = (f16)v1.z; o[7] = (f16)v1.w;
  *(f16x8*)(wf + (size_t)m * W_ELEMS + e) = o;
}

// ---------------- main: QKV GEMM (32x32x16) + 2x2 attention + residual ----------------
// Block (rb,h): 128 rows x 192 cols, K=768 (12 steps of 64). 4 waves, wave owns 32 rows.
// BOTH A and B staged via global_load_lds (vmcnt queue = staging ops ONLY: 10/wave/step).
// Pipeline: counted vmcnt + raw s_barrier (T3/T4) -- next tile's 10 loads stay in flight
// across the barrier; wait covers only the current tile, issued one full MFMA phase ago.
// LDS layout [row][slot] with CONTENT swizzle (slot c holds global chunk c ^ (row&7)),
// achieved by pre-swizzling the per-lane GLOBAL address (LDS dest stays lane-linear).
__global__ __launch_bounds__(256, 2) void qkv_attn_kernel(const f16* __restrict__ xn,
                                                          const f16* __restrict__ wf,
                                                          const float* __restrict__ x,
                                                          float* __restrict__ out) {
  __shared__ f16 sA[2][RB * 64]  __attribute__((aligned(16)));   // 32 KB
  __shared__ f16 sB[2][192 * 64] __attribute__((aligned(16)));   // 48 KB

  const int tid  = threadIdx.x;
  const int wave = tid >> 6;
  const int lane = tid & 63;
  const int l31  = lane & 31;
  const int hi   = lane >> 5;

  // XCD-bijective swizzle: each XCD gets 64 consecutive rb x all 12 h (xn L2 reuse)
  int bid = blockIdx.x;
  int my  = (bid & 7) * (NBLK / 8) + (bid >> 3);
  int rb  = my / H;
  int h   = my % H;

  const int ri = lane >> 3;   // staging row-in-op
  const int ci = lane & 7;    // staging LDS slot -> global chunk ci ^ ri

  // A staging: 4 ops/wave, op o = tile rows wave*32 + o*8 + ri
  const f16* abase = xn + (size_t)rb * RB * D;
  unsigned aoffs[4];
#pragma unroll
  for (int o = 0; o < 4; ++o)
    aoffs[o] = (unsigned)((wave * 32 + o * 8 + ri) * D + ((ci ^ ri) * 8));

  // B staging: 6 ops/wave, op o = tile rows wave*48 + o*8 + ri (q|k|v blocks of 64)
  unsigned boffs[6];
#pragma unroll
  for (int o = 0; o < 6; ++o) {
    int n = wave * 48 + o * 8 + ri;
    boffs[o] = (unsigned)((n >> 6) * (int)W_ELEMS + (h * 64 + (n & 63)) * D + ((ci ^ ri) * 8));
  }

  // fragment read offsets (content swizzle: chunk kc lives at slot kc ^ (row&7))
  const int q7 = l31 & 7;
  int aoff[4], coff[4];
#pragma unroll
  for (int s = 0; s < 4; ++s) {
    int kc = s * 2 + hi;
    aoff[s] = (wave * 32 + l31) * 64 + ((kc ^ q7) * 8);
    coff[s] = l31 * 64 + ((kc ^ q7) * 8);
  }

#define STAGE(KO, BUF)                                                                   \
  {                                                                                      \
    _Pragma("unroll") for (int o = 0; o < 4; ++o) {                                      \
      __builtin_amdgcn_global_load_lds((gvoid_t*)(abase + aoffs[o] + (KO) * 64),         \
                                       (lvoid_t*)(&sA[BUF][(wave * 32 + o * 8) * 64]),   \
                                       16, 0, 0);                                        \
    }                                                                                    \
    _Pragma("unroll") for (int o = 0; o < 6; ++o) {                                      \
      __builtin_amdgcn_global_load_lds((gvoid_t*)(wf + boffs[o] + (KO) * 64),            \
                                       (lvoid_t*)(&sB[BUF][(wave * 48 + o * 8) * 64]),   \
                                       16, 0, 0);                                        \
    }                                                                                    \
  }

  STAGE(0, 0);

  f32x16 acc[6];
#pragma unroll
  for (int t = 0; t < 6; ++t)
#pragma unroll
    for (int i = 0; i < 16; ++i) acc[t][i] = 0.f;

#pragma unroll
  for (int ko = 0; ko < 12; ++ko) {
    const int cur = ko & 1;
    if (ko < 11) STAGE(ko + 1, cur ^ 1);

    // tile-ready: wait ONLY for current tile's 10 ops (10 newer stay in flight), then barrier
    if (ko < 11) asm volatile("s_waitcnt vmcnt(10)\n\ts_barrier" ::: "memory");
    else         asm volatile("s_waitcnt vmcnt(0)\n\ts_barrier" ::: "memory");

    __builtin_amdgcn_s_setprio(1);
#pragma unroll
    for (int s = 0; s < 4; ++s) {
      f16x8 a = *(const f16x8*)(&sA[cur][aoff[s]]);
#pragma unroll
      for (int t = 0; t < 6; ++t) {
        f16x8 b = *(const f16x8*)(&sB[cur][coff[s] + t * 2048]);
        acc[t] = __builtin_amdgcn_mfma_f32_32x32x16_f16(a, b, acc[t], 0, 0, 0);
      }
    }
    __builtin_amdgcn_s_setprio(0);

    // reads of buf(cur) done before next iteration issues staging INTO buf(cur)
    if (ko < 11) asm volatile("s_barrier" ::: "memory");
  }

  // ---- epilogue: 2x2 attention per row, in-register (verified layout) ----
  // C/D: col = t*32 + l31, row-in-wave = (g&3) + 8*(g>>2) + 4*hi
  // t: 0=q_p0 1=q_p1 2=k_p0 3=k_p1 4=v_p0 5=v_p1 ; dk = l31
  {
    const size_t grow0 = (size_t)rb * RB + wave * 32;
    const float scale = 0.17677669529663687f;  // 1/sqrt(32)
#pragma unroll
    for (int g = 0; g < 16; ++g) {
      float q0 = acc[0][g], q1 = acc[1][g];
      float k0 = acc[2][g], k1 = acc[3][g];
      float s00 = q0 * k0, s01 = q0 * k1, s10 = q1 * k0, s11 = q1 * k1;
#pragma unroll
      for (int d2 = 1; d2 <= 16; d2 <<= 1) {
        s00 += __shfl_xor(s00, d2, 64);
        s01 += __shfl_xor(s01, d2, 64);
        s10 += __shfl_xor(s10, d2, 64);
        s11 += __shfl_xor(s11, d2, 64);
      }
      s00 *= scale; s01 *= scale; s10 *= scale; s11 *= scale;
      float mx0 = fmaxf(s00, s01);
      float e00 = __expf(s00 - mx0), e01 = __expf(s01 - mx0);
      float r0 = 1.0f / (e00 + e01);
      float a00 = e00 * r0, a01 = e01 * r0;
      float mx1 = fmaxf(s10, s11);
      float e10 = __expf(s10 - mx1), e11 = __expf(s11 - mx1);
      float r1 = 1.0f / (e10 + e11);
      float a10 = e10 * r1, a11 = e11 * r1;

      int row_w = (g & 3) + 8 * (g >> 2) + 4 * hi;
      const float* xp = x   + (grow0 + row_w) * D + h * 64 + l31;
      float*       op = out + (grow0 + row_w) * D + h * 64 + l31;
      float v0 = acc[4][g], v1 = acc[5][g];
      op[0]  = a00 * v0 + a01 * v1 + xp[0];    // p0: col h*64 + dk
      op[32] = a10 * v0 + a11 * v1 + xp[32];   // p1: col h*64 + 32 + dk
    }
  }
#undef STAGE
}

extern "C" void kernel_launch(void* const* d_in, const int* in_sizes, int n_in,
                              void* d_out, int out_size, void* d_ws, size_t ws_size,
                              hipStream_t stream) {
  const float* x     = (const float*)d_in[0];
  const float* Wq    = (const float*)d_in[1];
  const float* Wk    = (const float*)d_in[2];
  const float* Wv    = (const float*)d_in[3];
  const float* gamma = (const float*)d_in[4];
  const float* beta  = (const float*)d_in[5];
  float* out = (float*)d_out;
  (void)in_sizes; (void)n_in; (void)out_size; (void)ws_size;

  f16* xn = (f16*)d_ws;                 // 100.7 MB
  f16* wf = xn + XN_ELEMS;              // + 3.5 MB  (needs ws_size >= ~104.3 MB)

  ln_kernel<<<dim3(BS / 8), dim3(256), 0, stream>>>(x, gamma, beta, xn);
  wconv_kernel<<<dim3(864), dim3(256), 0, stream>>>(Wq, Wk, Wv, wf);
  qkv_attn_kernel<<<dim3(NBLK), dim3(256), 0, stream>>>(xn, wf, x, out);
}

// Round 6
// 643.793 us; speedup vs baseline: 1.1236x; 1.1236x over previous
//
#include <hip/hip_runtime.h>

typedef _Float16 f16;
typedef _Float16 f16x8 __attribute__((ext_vector_type(8)));
typedef float f32x16 __attribute__((ext_vector_type(16)));

#define BS 65536
#define D 768
#define H 12
#define RB 128                   // rows per main block
#define NBLK ((BS / RB) * H)     // 6144
#define W_ELEMS ((size_t)D * D)
#define XN_ELEMS ((size_t)BS * D)

typedef const __attribute__((address_space(1))) void gvoid_t;
typedef __attribute__((address_space(3))) void lvoid_t;

// Packed xn layout (exact MFMA A-frag order for 32x32x16):
//   elem(row, k) at  ((row>>5)*12 + (k>>6))*2048 + ((k>>4)&3)*512 + ((k>>3)&1)*256 + (row&31)*8 + (k&7)
// -> a wave's A-frag load for one (ko,s) is ONE contiguous 1024B transaction.

// ---------------- prepass 1: LayerNorm -> packed xn (f16, gamma/beta folded) ----------------
// 16 rows/block, 16 threads/row (thread owns 48 contiguous f32, held in regs; x read once).
__global__ __launch_bounds__(256, 4) void ln_kernel(const float* __restrict__ x,
                                                    const float* __restrict__ gamma,
                                                    const float* __restrict__ beta,
                                                    f16* __restrict__ xp) {
  __shared__ float sSum[16][17], sSq[16][17];
  const int tid = threadIdx.x;
  const int r  = tid & 15;    // row in block
  const int sg = tid >> 4;    // segment: f32 [sg*48, sg*48+48)
  const size_t R = (size_t)blockIdx.x * 16 + r;
  const float4* xs = (const float4*)(x + R * D + sg * 48);
  float4 v[12];
  float sum = 0.f, sq = 0.f;
#pragma unroll
  for (int j = 0; j < 12; ++j) {
    v[j] = xs[j];
    sum += (v[j].x + v[j].y) + (v[j].z + v[j].w);
    sq  += v[j].x * v[j].x + v[j].y * v[j].y + v[j].z * v[j].z + v[j].w * v[j].w;
  }
  sSum[sg][r] = sum; sSq[sg][r] = sq;
  __syncthreads();
  float ts = 0.f, tq = 0.f;
#pragma unroll
  for (int k = 0; k < 16; ++k) { ts += sSum[k][r]; tq += sSq[k][r]; }
  const float mu   = ts * (1.0f / D);
  const float rstd = rsqrtf(tq * (1.0f / D) - mu * mu + 1e-6f);

  const float4* g4 = (const float4*)(gamma + sg * 48);
  const float4* b4 = (const float4*)(beta  + sg * 48);
  const int rb12 = (int)(R >> 5) * 12;
  const int r31  = (int)(R & 31);
#pragma unroll
  for (int jj = 0; jj < 6; ++jj) {
    const int k = sg * 48 + jj * 8;
    float4 g0 = g4[2 * jj], g1 = g4[2 * jj + 1];
    float4 b0 = b4[2 * jj], b1 = b4[2 * jj + 1];
    float4 u0 = v[2 * jj],  u1 = v[2 * jj + 1];
    f16x8 o;
    o[0] = (f16)((u0.x - mu) * rstd * g0.x + b0.x);
    o[1] = (f16)((u0.y - mu) * rstd * g0.y + b0.y);
    o[2] = (f16)((u0.z - mu) * rstd * g0.z + b0.z);
    o[3] = (f16)((u0.w - mu) * rstd * g0.w + b0.w);
    o[4] = (f16)((u1.x - mu) * rstd * g1.x + b1.x);
    o[5] = (f16)((u1.y - mu) * rstd * g1.y + b1.y);
    o[6] = (f16)((u1.z - mu) * rstd * g1.z + b1.z);
    o[7] = (f16)((u1.w - mu) * rstd * g1.w + b1.w);
    size_t addr = ((size_t)(rb12 + (k >> 6))) * 2048 + ((k >> 4) & 3) * 512
                + ((k >> 3) & 1) * 256 + r31 * 8;
    *(f16x8*)(xp + addr) = o;
  }
}

// ---------------- prepass 2: W f32 -> f16 ----------------
__global__ __launch_bounds__(256, 4) void wconv_kernel(const float* __restrict__ Wq,
                                                       const float* __restrict__ Wk,
                                                       const float* __restrict__ Wv,
                                                       f16* __restrict__ wf) {
  int b = blockIdx.x;          // 0..863 (3 * 288)
  int m = b / 288;
  size_t e = ((size_t)(b % 288) * 256 + threadIdx.x) * 8;
  const float* src = (m == 0 ? Wq : (m == 1 ? Wk : Wv)) + e;
  float4 v0 = *(const float4*)src;
  float4 v1 = *(const float4*)(src + 4);
  f16x8 o;
  o[0] = (f16)v0.x; o[1] = (f16)v0.y; o[2] = (f16)v0.z; o[3] = (f16)v0.w;
  o[4] = (f16)v1.x; o[5] = (f16)v1.y; o[6] = (f16)v1.z; o[7] = (f16)v1.w;
  *(f16x8*)(wf + (size_t)m * W_ELEMS + e) = o;
}

// ---------------- main: QKV GEMM (32x32x16) + 2x2 attention + residual ----------------
// R2 structure (best measured: 380us): 128 rows x 192 cols, 4 waves, A in regs, B via
// global_load_lds into 48KB double-buffered LDS -> 3 blocks/CU (enforced by bounds(256,3)).
// Counted vmcnt with correct issue ORDER (A-loads first, then stage, then wait(10)) so
// next tile's 6 staging ops stay in flight across the barrier; A from packed xn (coalesced).
__global__ __launch_bounds__(256, 3) void qkv_attn_kernel(const f16* __restrict__ xp,
                                                          const f16* __restrict__ wf,
                                                          const float* __restrict__ x,
                                                          float* __restrict__ out) {
  __shared__ f16 sB[2][192 * 64] __attribute__((aligned(16)));   // 48 KB

  const int tid  = threadIdx.x;
  const int wave = tid >> 6;
  const int lane = tid & 63;
  const int l31  = lane & 31;
  const int hi   = lane >> 5;

  // XCD-bijective swizzle: 12 head-blocks of one rb land on the same XCD (xn L2 reuse)
  int bid = blockIdx.x;
  int my  = (bid & 7) * (NBLK / 8) + (bid >> 3);
  int rb  = my / H;
  int h   = my % H;

  const int ri = lane >> 3;   // staging row-in-op
  const int ci = lane & 7;    // staging LDS slot -> global chunk ci ^ ri

  // B staging: 6 ops/wave, op o = tile rows wave*48 + o*8 + ri (q|k|v blocks of 64)
  unsigned boffs[6];
#pragma unroll
  for (int o = 0; o < 6; ++o) {
    int n = wave * 48 + o * 8 + ri;
    boffs[o] = (unsigned)((n >> 6) * (int)W_ELEMS + (h * 64 + (n & 63)) * D + ((ci ^ ri) * 8));
  }

  // B-frag read offsets (content swizzle: chunk kc at slot kc ^ (row&7))
  const int q7 = l31 & 7;
  int coff[4];
#pragma unroll
  for (int s = 0; s < 4; ++s) coff[s] = l31 * 64 + (((s * 2 + hi) ^ q7) * 8);

  // A base in packed xn: row-group rb*4 + wave, lane part hi*256 + l31*8
  const f16* ap = xp + ((size_t)(rb * 4 + wave) * 12) * 2048 + hi * 256 + l31 * 8;

#define STAGE(KO, BUF)                                                                   \
  {                                                                                      \
    _Pragma("unroll") for (int o = 0; o < 6; ++o) {                                      \
      __builtin_amdgcn_global_load_lds((gvoid_t*)(wf + boffs[o] + (KO) * 64),            \
                                       (lvoid_t*)(&sB[BUF][(wave * 48 + o * 8) * 64]),   \
                                       16, 0, 0);                                        \
    }                                                                                    \
  }

  STAGE(0, 0);

  f32x16 acc[6];
#pragma unroll
  for (int t = 0; t < 6; ++t)
#pragma unroll
    for (int i = 0; i < 16; ++i) acc[t][i] = 0.f;

#pragma unroll
  for (int ko = 0; ko < 12; ++ko) {
    const int cur = ko & 1;

    // 1) this step's A-frags (4 coalesced 1024B wave-loads) -- issued BEFORE staging so
    //    in-order vmcnt retirement lets the compiler's pre-MFMA wait leave staging in flight
    f16x8 a0 = *(const f16x8*)(ap + ko * 2048);
    f16x8 a1 = *(const f16x8*)(ap + ko * 2048 + 512);
    f16x8 a2 = *(const f16x8*)(ap + ko * 2048 + 1024);
    f16x8 a3 = *(const f16x8*)(ap + ko * 2048 + 1536);
    __builtin_amdgcn_sched_barrier(0);
    // 2) next tile's staging (6 ops -> buf cur^1)
    if (ko < 11) STAGE(ko + 1, cur ^ 1);
    __builtin_amdgcn_sched_barrier(0);
    // 3) tile-ready: drain stage(ko) only (newer ops stay in flight), then barrier
    if (ko < 11) asm volatile("s_waitcnt vmcnt(10)" ::: "memory");
    else         asm volatile("s_waitcnt vmcnt(4)" ::: "memory");
    __builtin_amdgcn_sched_barrier(0);
    __builtin_amdgcn_s_barrier();

    __builtin_amdgcn_s_setprio(1);
    {
      f16x8 b;
#pragma unroll
      for (int t = 0; t < 6; ++t) {
        b = *(const f16x8*)(&sB[cur][coff[0] + t * 2048]);
        acc[t] = __builtin_amdgcn_mfma_f32_32x32x16_f16(a0, b, acc[t], 0, 0, 0);
      }
#pragma unroll
      for (int t = 0; t < 6; ++t) {
        b = *(const f16x8*)(&sB[cur][coff[1] + t * 2048]);
        acc[t] = __builtin_amdgcn_mfma_f32_32x32x16_f16(a1, b, acc[t], 0, 0, 0);
      }
#pragma unroll
      for (int t = 0; t < 6; ++t) {
        b = *(const f16x8*)(&sB[cur][coff[2] + t * 2048]);
        acc[t] = __builtin_amdgcn_mfma_f32_32x32x16_f16(a2, b, acc[t], 0, 0, 0);
      }
#pragma unroll
      for (int t = 0; t < 6; ++t) {
        b = *(const f16x8*)(&sB[cur][coff[3] + t * 2048]);
        acc[t] = __builtin_amdgcn_mfma_f32_32x32x16_f16(a3, b, acc[t], 0, 0, 0);
      }
    }
    __builtin_amdgcn_s_setprio(0);

    // reads of buf(cur) done before next iteration stages INTO buf(cur)
    if (ko < 11) {
      asm volatile("s_waitcnt lgkmcnt(0)" ::: "memory");
      __builtin_amdgcn_sched_barrier(0);
      __builtin_amdgcn_s_barrier();
    }
  }

  // ---- epilogue: 2x2 attention per row, in-register (verified layout) ----
  // C/D: col = t*32 + l31, row-in-wave = (g&3) + 8*(g>>2) + 4*hi
  // t: 0=q_p0 1=q_p1 2=k_p0 3=k_p1 4=v_p0 5=v_p1 ; dk = l31
  {
    const size_t grow0 = (size_t)rb * RB + wave * 32;
    const float scale = 0.17677669529663687f;  // 1/sqrt(32)
#pragma unroll
    for (int g = 0; g < 16; ++g) {
      float q0 = acc[0][g], q1 = acc[1][g];
      float k0 = acc[2][g], k1 = acc[3][g];
      float s00 = q0 * k0, s01 = q0 * k1, s10 = q1 * k0, s11 = q1 * k1;
#pragma unroll
      for (int d2 = 1; d2 <= 16; d2 <<= 1) {
        s00 += __shfl_xor(s00, d2, 64);
        s01 += __shfl_xor(s01, d2, 64);
        s10 += __shfl_xor(s10, d2, 64);
        s11 += __shfl_xor(s11, d2, 64);
      }
      s00 *= scale; s01 *= scale; s10 *= scale; s11 *= scale;
      float mx0 = fmaxf(s00, s01);
      float e00 = __expf(s00 - mx0), e01 = __expf(s01 - mx0);
      float r0 = 1.0f / (e00 + e01);
      float a00 = e00 * r0, a01 = e01 * r0;
      float mx1 = fmaxf(s10, s11);
      float e10 = __expf(s10 - mx1), e11 = __expf(s11 - mx1);
      float r1 = 1.0f / (e10 + e11);
      float a10 = e10 * r1, a11 = e11 * r1;

      int row_w = (g & 3) + 8 * (g >> 2) + 4 * hi;
      const float* xq = x   + (grow0 + row_w) * D + h * 64 + l31;
      float*       op = out + (grow0 + row_w) * D + h * 64 + l31;
      float v0 = acc[4][g], v1 = acc[5][g];
      op[0]  = a00 * v0 + a01 * v1 + xq[0];    // p0: col h*64 + dk
      op[32] = a10 * v0 + a11 * v1 + xq[32];   // p1: col h*64 + 32 + dk
    }
  }
#undef STAGE
}

extern "C" void kernel_launch(void* const* d_in, const int* in_sizes, int n_in,
                              void* d_out, int out_size, void* d_ws, size_t ws_size,
                              hipStream_t stream) {
  const float* x     = (const float*)d_in[0];
  const float* Wq    = (const float*)d_in[1];
  const float* Wk    = (const float*)d_in[2];
  const float* Wv    = (const float*)d_in[3];
  const float* gamma = (const float*)d_in[4];
  const float* beta  = (const float*)d_in[5];
  float* out = (float*)d_out;
  (void)in_sizes; (void)n_in; (void)out_size; (void)ws_size;

  f16* xp = (f16*)d_ws;                 // 100.7 MB (packed xn)
  f16* wf = xp + XN_ELEMS;              // + 3.5 MB  (needs ws_size >= ~104.3 MB)

  ln_kernel<<<dim3(BS / 16), dim3(256), 0, stream>>>(x, gamma, beta, xp);
  wconv_kernel<<<dim3(864), dim3(256), 0, stream>>>(Wq, Wk, Wv, wf);
  qkv_attn_kernel<<<dim3(NBLK), dim3(256), 0, stream>>>(xp, wf, x, out);
}